// Round 7
// baseline (49.214 us; speedup 1.0000x reference)
//
#include <hip/hip_runtime.h>
#include <hip/hip_bf16.h>

typedef __attribute__((ext_vector_type(4))) float f32x4;
typedef __attribute__((ext_vector_type(4))) double f64x4;
typedef __attribute__((ext_vector_type(8))) short short8;

#define NA 1024
#define NB 1024
#define KF 256
#define DIM 128
#define GRID 256

// Fused: Phase A (proj via f64 MFMA, probe-decoded D layout) -> device barrier ->
// Phase B (out = P @ M^T via bf16 MFMA). Grid = 256 = 1 block/CU (co-resident by
// construction: 68 KB LDS, 256 threads). Barrier counter in d_ws @ +1MB, zeroed
// by hipMemsetAsync each call (graph memset node) -> poison-proof, deterministic.

union SharedU {
    struct { float Xs[32][132]; float Fs[64][132]; } pa;   // 50.7 KB
    struct { short LA[64][264]; short LB[64][264]; } pb;   // 67.6 KB
};

__global__ __launch_bounds__(256) void fused_kernel(
    const float* __restrict__ a, const float* __restrict__ b,
    const float* __restrict__ feats,
    __hip_bfloat16* __restrict__ P, __hip_bfloat16* __restrict__ M,
    unsigned int* __restrict__ cnt,
    float* __restrict__ out)
{
    __shared__ SharedU sh;
    const int t = threadIdx.x;
    const int bb = blockIdx.x;

    // ================= Phase A: fk = X @ feats^T -> P(relu), M(mask<=0) =========
    {
        const int rb = bb >> 2;            // 0..63: 32-row group of concat [a;b]
        const int cb = bb & 3;             // 0..3 : 64-col group of fk
        const int row0 = rb * 32;
        const int col0 = cb * 64;
        const bool isA = row0 < NA;
        const float* __restrict__ src = isA ? a : b;
        const int r0 = isA ? row0 : row0 - NA;

        // stage X: 32 rows x 32 f32x4 chunks = 1024, 4/thread (coalesced)
#pragma unroll
        for (int i = 0; i < 4; ++i) {
            int idx = t + i * 256;
            int r = idx >> 5, c4 = idx & 31;
            *(f32x4*)&sh.pa.Xs[r][c4 * 4] =
                *(const f32x4*)(src + (size_t)(r0 + r) * DIM + c4 * 4);
        }
        // stage F: 64 rows x 32 chunks = 2048, 8/thread
#pragma unroll
        for (int i = 0; i < 8; ++i) {
            int idx = t + i * 256;
            int r = idx >> 5, c4 = idx & 31;
            *(f32x4*)&sh.pa.Fs[r][c4 * 4] =
                *(const f32x4*)(feats + (size_t)(col0 + r) * DIM + c4 * 4);
        }
        __syncthreads();

        const int l = t & 63, w = t >> 6;
        const int fr = l & 15, fq = l >> 4;

        // layout probe: probe[r] = 4*m + 256*n for this lane's acc slot r
        f64x4 probe = {0.0, 0.0, 0.0, 0.0};
        probe = __builtin_amdgcn_mfma_f64_16x16x4f64((double)fr, 1.0, probe, 0, 0, 0);
        probe = __builtin_amdgcn_mfma_f64_16x16x4f64(1.0, 64.0 * (double)fr, probe, 0, 0, 0);

        // wave w: rows [16*(w&1), +16), cols [32*(w>>1), +32) as 2 16-col tiles
        const int wrow = (w & 1) * 16;
        const int wcol = (w >> 1) * 32;
        const float* __restrict__ xr  = &sh.pa.Xs[wrow + fr][fq];
        const float* __restrict__ fp0 = &sh.pa.Fs[wcol + fr][fq];
        const float* __restrict__ fp1 = &sh.pa.Fs[wcol + 16 + fr][fq];

        // 4 independent chains: 2 tiles x 2 parities (covers f64 MFMA latency)
        f64x4 acc[2][2] = {{{0.,0.,0.,0.},{0.,0.,0.,0.}},{{0.,0.,0.,0.},{0.,0.,0.,0.}}};
#pragma unroll
        for (int s = 0; s < 32; s += 2) {
            double x0 = (double)xr[s * 4],     x1 = (double)xr[s * 4 + 4];
            double f00 = (double)fp0[s * 4],   f01 = (double)fp0[s * 4 + 4];
            double f10 = (double)fp1[s * 4],   f11 = (double)fp1[s * 4 + 4];
            acc[0][0] = __builtin_amdgcn_mfma_f64_16x16x4f64(x0, f00, acc[0][0], 0, 0, 0);
            acc[1][0] = __builtin_amdgcn_mfma_f64_16x16x4f64(x0, f10, acc[1][0], 0, 0, 0);
            acc[0][1] = __builtin_amdgcn_mfma_f64_16x16x4f64(x1, f01, acc[0][1], 0, 0, 0);
            acc[1][1] = __builtin_amdgcn_mfma_f64_16x16x4f64(x1, f11, acc[1][1], 0, 0, 0);
        }

#pragma unroll
        for (int tt = 0; tt < 2; ++tt) {
#pragma unroll
            for (int r = 0; r < 4; ++r) {
                int code = (int)probe[r];
                int m = (code >> 2) & 15;
                int n = code >> 8;
                double v = acc[tt][0][r] + acc[tt][1][r];
                size_t off = (size_t)(r0 + wrow + m) * KF + col0 + wcol + tt * 16 + n;
                if (isA) {
                    float vr = (v > 0.0) ? (float)v : 0.0f;
                    P[off] = __float2bfloat16(vr);
                } else {
                    float vr = (v <= 0.0) ? 1.0f : 0.0f;
                    M[off] = __float2bfloat16(vr);
                }
            }
        }
    }

    // ================= device-scope barrier =====================================
    __threadfence();
    __syncthreads();
    if (t == 0) {
        __hip_atomic_fetch_add(cnt, 1u, __ATOMIC_ACQ_REL, __HIP_MEMORY_SCOPE_AGENT);
        while (__hip_atomic_load(cnt, __ATOMIC_ACQUIRE, __HIP_MEMORY_SCOPE_AGENT) < GRID) {
            __builtin_amdgcn_s_sleep(1);
        }
    }
    __syncthreads();

    // ================= Phase B: out = P @ M^T ===================================
    {
        const int row0 = (bb >> 4) * 64;
        const int col0 = (bb & 15) * 64;
        const short* Pa = (const short*)P;
        const short* Mb = (const short*)M;

#pragma unroll
        for (int i = 0; i < 8; ++i) {
            int c = t + i * 256;
            int row = c >> 5;
            int c8 = (c & 31) << 3;
            *(short8*)&sh.pb.LA[row][c8] = *(const short8*)(Pa + (size_t)(row0 + row) * KF + c8);
            *(short8*)&sh.pb.LB[row][c8] = *(const short8*)(Mb + (size_t)(col0 + row) * KF + c8);
        }
        __syncthreads();

        const int lane = t & 63;
        const int wid = t >> 6;
        const int wr = (wid >> 1) * 32;
        const int wc = (wid & 1) * 32;
        const int fr = lane & 15;
        const int fq = lane >> 4;

        f32x4 acc[2][2];
#pragma unroll
        for (int m = 0; m < 2; ++m)
#pragma unroll
            for (int n = 0; n < 2; ++n)
                acc[m][n] = (f32x4){0.f, 0.f, 0.f, 0.f};

#pragma unroll
        for (int kk = 0; kk < KF / 32; ++kk) {
            const int kb = kk * 32 + fq * 8;
            short8 a0 = *(const short8*)&sh.pb.LA[wr + fr][kb];
            short8 a1 = *(const short8*)&sh.pb.LA[wr + 16 + fr][kb];
            short8 b0 = *(const short8*)&sh.pb.LB[wc + fr][kb];
            short8 b1 = *(const short8*)&sh.pb.LB[wc + 16 + fr][kb];
            acc[0][0] = __builtin_amdgcn_mfma_f32_16x16x32_bf16(a0, b0, acc[0][0], 0, 0, 0);
            acc[0][1] = __builtin_amdgcn_mfma_f32_16x16x32_bf16(a0, b1, acc[0][1], 0, 0, 0);
            acc[1][0] = __builtin_amdgcn_mfma_f32_16x16x32_bf16(a1, b0, acc[1][0], 0, 0, 0);
            acc[1][1] = __builtin_amdgcn_mfma_f32_16x16x32_bf16(a1, b1, acc[1][1], 0, 0, 0);
        }

#pragma unroll
        for (int m = 0; m < 2; ++m)
#pragma unroll
            for (int n = 0; n < 2; ++n)
#pragma unroll
                for (int r = 0; r < 4; ++r) {
                    int row = row0 + wr + m * 16 + fq * 4 + r;
                    int col = col0 + wc + n * 16 + fr;
                    out[(size_t)row * NB + col] = acc[m][n][r];
                }
    }
}

extern "C" void kernel_launch(void* const* d_in, const int* in_sizes, int n_in,
                              void* d_out, int out_size, void* d_ws, size_t ws_size,
                              hipStream_t stream) {
    const float* a = (const float*)d_in[0];
    const float* b = (const float*)d_in[1];
    const float* feats = (const float*)d_in[2];
    float* out = (float*)d_out;
    __hip_bfloat16* P = (__hip_bfloat16*)d_ws;                     // 512 KB
    __hip_bfloat16* M = P + (size_t)NA * KF;                       // 512 KB
    unsigned int* cnt = (unsigned int*)((char*)d_ws + (1u << 20)); // @ +1 MB

    hipMemsetAsync(cnt, 0, sizeof(unsigned int), stream);
    fused_kernel<<<dim3(GRID), dim3(256), 0, stream>>>(a, b, feats, P, M, cnt, out);
}

// Round 8
// 34.789 us; speedup vs baseline: 1.4146x; 1.4146x over previous
//
#include <hip/hip_runtime.h>
#include <hip/hip_bf16.h>

typedef __attribute__((ext_vector_type(4))) float f32x4;
typedef __attribute__((ext_vector_type(4))) double f64x4;
typedef __attribute__((ext_vector_type(8))) short short8;

#define NA 1024
#define NB 1024
#define KF 256
#define DIM 128
#define GRID 256

// Fused: Phase A (proj via f64 MFMA, probe-decoded D layout) -> device barrier ->
// Phase B (out = P @ M^T via bf16 MFMA). Grid = 256 = 1 block/CU (co-resident).
// Barrier R8 fix: thread0-only release fence (ONE L2 writeback/block), RELAXED
// polling (no per-poll invalidate), ONE acquire invalidate at exit. R7's version
// did an L2 writeback per THREAD and an L2 invalidate per POLL -> 40us of cache
// thrash.

union SharedU {
    struct { float Xs[32][132]; float Fs[64][132]; } pa;   // 50.7 KB
    struct { short LA[64][264]; short LB[64][264]; } pb;   // 67.6 KB
};

__global__ __launch_bounds__(256) void fused_kernel(
    const float* __restrict__ a, const float* __restrict__ b,
    const float* __restrict__ feats,
    __hip_bfloat16* __restrict__ P, __hip_bfloat16* __restrict__ M,
    unsigned int* __restrict__ cnt,
    float* __restrict__ out)
{
    __shared__ SharedU sh;
    const int t = threadIdx.x;
    const int bb = blockIdx.x;

    // ================= Phase A: fk = X @ feats^T -> P(relu), M(mask<=0) =========
    {
        const int rb = bb >> 2;            // 0..63: 32-row group of concat [a;b]
        const int cb = bb & 3;             // 0..3 : 64-col group of fk
        const int row0 = rb * 32;
        const int col0 = cb * 64;
        const bool isA = row0 < NA;
        const float* __restrict__ src = isA ? a : b;
        const int r0 = isA ? row0 : row0 - NA;

        // stage X: 32 rows x 32 f32x4 chunks = 1024, 4/thread (coalesced)
#pragma unroll
        for (int i = 0; i < 4; ++i) {
            int idx = t + i * 256;
            int r = idx >> 5, c4 = idx & 31;
            *(f32x4*)&sh.pa.Xs[r][c4 * 4] =
                *(const f32x4*)(src + (size_t)(r0 + r) * DIM + c4 * 4);
        }
        // stage F: 64 rows x 32 chunks = 2048, 8/thread
#pragma unroll
        for (int i = 0; i < 8; ++i) {
            int idx = t + i * 256;
            int r = idx >> 5, c4 = idx & 31;
            *(f32x4*)&sh.pa.Fs[r][c4 * 4] =
                *(const f32x4*)(feats + (size_t)(col0 + r) * DIM + c4 * 4);
        }
        __syncthreads();

        const int l = t & 63, w = t >> 6;
        const int fr = l & 15, fq = l >> 4;

        // layout probe: probe[r] = 4*m + 256*n for this lane's acc slot r
        f64x4 probe = {0.0, 0.0, 0.0, 0.0};
        probe = __builtin_amdgcn_mfma_f64_16x16x4f64((double)fr, 1.0, probe, 0, 0, 0);
        probe = __builtin_amdgcn_mfma_f64_16x16x4f64(1.0, 64.0 * (double)fr, probe, 0, 0, 0);

        // wave w: rows [16*(w&1), +16), cols [32*(w>>1), +32) as 2 16-col tiles
        const int wrow = (w & 1) * 16;
        const int wcol = (w >> 1) * 32;
        const float* __restrict__ xr  = &sh.pa.Xs[wrow + fr][fq];
        const float* __restrict__ fp0 = &sh.pa.Fs[wcol + fr][fq];
        const float* __restrict__ fp1 = &sh.pa.Fs[wcol + 16 + fr][fq];

        // 4 independent chains: 2 tiles x 2 parities (covers f64 MFMA latency)
        f64x4 acc[2][2] = {{{0.,0.,0.,0.},{0.,0.,0.,0.}},{{0.,0.,0.,0.},{0.,0.,0.,0.}}};
#pragma unroll
        for (int s = 0; s < 32; s += 2) {
            double x0 = (double)xr[s * 4],     x1 = (double)xr[s * 4 + 4];
            double f00 = (double)fp0[s * 4],   f01 = (double)fp0[s * 4 + 4];
            double f10 = (double)fp1[s * 4],   f11 = (double)fp1[s * 4 + 4];
            acc[0][0] = __builtin_amdgcn_mfma_f64_16x16x4f64(x0, f00, acc[0][0], 0, 0, 0);
            acc[1][0] = __builtin_amdgcn_mfma_f64_16x16x4f64(x0, f10, acc[1][0], 0, 0, 0);
            acc[0][1] = __builtin_amdgcn_mfma_f64_16x16x4f64(x1, f01, acc[0][1], 0, 0, 0);
            acc[1][1] = __builtin_amdgcn_mfma_f64_16x16x4f64(x1, f11, acc[1][1], 0, 0, 0);
        }

#pragma unroll
        for (int tt = 0; tt < 2; ++tt) {
#pragma unroll
            for (int r = 0; r < 4; ++r) {
                int code = (int)probe[r];
                int m = (code >> 2) & 15;
                int n = code >> 8;
                double v = acc[tt][0][r] + acc[tt][1][r];
                size_t off = (size_t)(r0 + wrow + m) * KF + col0 + wcol + tt * 16 + n;
                if (isA) {
                    float vr = (v > 0.0) ? (float)v : 0.0f;
                    P[off] = __float2bfloat16(vr);
                } else {
                    float vr = (v <= 0.0) ? 1.0f : 0.0f;
                    M[off] = __float2bfloat16(vr);
                }
            }
        }
    }

    // ================= device-scope barrier (thread0-only cache ops) ============
    __syncthreads();   // all P/M stores issued + vmcnt drained before s_barrier
    if (t == 0) {
        __threadfence();   // ONE release (L2 writeback) per block
        __hip_atomic_fetch_add(cnt, 1u, __ATOMIC_RELAXED, __HIP_MEMORY_SCOPE_AGENT);
        while (__hip_atomic_load(cnt, __ATOMIC_RELAXED, __HIP_MEMORY_SCOPE_AGENT) < GRID) {
            __builtin_amdgcn_s_sleep(8);   // ~512 cyc between polls, no cache ops
        }
        // ONE acquire (L2 invalidate) per block after the barrier opens
        (void)__hip_atomic_load(cnt, __ATOMIC_ACQUIRE, __HIP_MEMORY_SCOPE_AGENT);
    }
    __syncthreads();

    // ================= Phase B: out = P @ M^T ===================================
    {
        const int row0 = (bb >> 4) * 64;
        const int col0 = (bb & 15) * 64;
        const short* Pa = (const short*)P;
        const short* Mb = (const short*)M;

#pragma unroll
        for (int i = 0; i < 8; ++i) {
            int c = t + i * 256;
            int row = c >> 5;
            int c8 = (c & 31) << 3;
            *(short8*)&sh.pb.LA[row][c8] = *(const short8*)(Pa + (size_t)(row0 + row) * KF + c8);
            *(short8*)&sh.pb.LB[row][c8] = *(const short8*)(Mb + (size_t)(col0 + row) * KF + c8);
        }
        __syncthreads();

        const int lane = t & 63;
        const int wid = t >> 6;
        const int wr = (wid >> 1) * 32;
        const int wc = (wid & 1) * 32;
        const int fr = lane & 15;
        const int fq = lane >> 4;

        f32x4 acc[2][2];
#pragma unroll
        for (int m = 0; m < 2; ++m)
#pragma unroll
            for (int n = 0; n < 2; ++n)
                acc[m][n] = (f32x4){0.f, 0.f, 0.f, 0.f};

#pragma unroll
        for (int kk = 0; kk < KF / 32; ++kk) {
            const int kb = kk * 32 + fq * 8;
            short8 a0 = *(const short8*)&sh.pb.LA[wr + fr][kb];
            short8 a1 = *(const short8*)&sh.pb.LA[wr + 16 + fr][kb];
            short8 b0 = *(const short8*)&sh.pb.LB[wc + fr][kb];
            short8 b1 = *(const short8*)&sh.pb.LB[wc + 16 + fr][kb];
            acc[0][0] = __builtin_amdgcn_mfma_f32_16x16x32_bf16(a0, b0, acc[0][0], 0, 0, 0);
            acc[0][1] = __builtin_amdgcn_mfma_f32_16x16x32_bf16(a0, b1, acc[0][1], 0, 0, 0);
            acc[1][0] = __builtin_amdgcn_mfma_f32_16x16x32_bf16(a1, b0, acc[1][0], 0, 0, 0);
            acc[1][1] = __builtin_amdgcn_mfma_f32_16x16x32_bf16(a1, b1, acc[1][1], 0, 0, 0);
        }

#pragma unroll
        for (int m = 0; m < 2; ++m)
#pragma unroll
            for (int n = 0; n < 2; ++n)
#pragma unroll
                for (int r = 0; r < 4; ++r) {
                    int row = row0 + wr + m * 16 + fq * 4 + r;
                    int col = col0 + wc + n * 16 + fr;
                    out[(size_t)row * NB + col] = acc[m][n][r];
                }
    }
}

extern "C" void kernel_launch(void* const* d_in, const int* in_sizes, int n_in,
                              void* d_out, int out_size, void* d_ws, size_t ws_size,
                              hipStream_t stream) {
    const float* a = (const float*)d_in[0];
    const float* b = (const float*)d_in[1];
    const float* feats = (const float*)d_in[2];
    float* out = (float*)d_out;
    __hip_bfloat16* P = (__hip_bfloat16*)d_ws;                     // 512 KB
    __hip_bfloat16* M = P + (size_t)NA * KF;                       // 512 KB
    unsigned int* cnt = (unsigned int*)((char*)d_ws + (1u << 20)); // @ +1 MB

    hipMemsetAsync(cnt, 0, sizeof(unsigned int), stream);
    fused_kernel<<<dim3(GRID), dim3(256), 0, stream>>>(a, b, feats, P, M, cnt, out);
}